// Round 10
// baseline (431.442 us; speedup 1.0000x reference)
//
#include <hip/hip_runtime.h>
#include <hip/hip_fp16.h>

namespace {

constexpr int BATCH = 8;
constexpr int SLEN  = 262144;
constexpr int TT    = 1023;   // (262144-512)/256 + 1
constexpr int NF    = 257;    // rfft bins
constexpr int RL    = 264;    // padded row length (halfs); pads [257,264) = 0
constexpr int NCH   = 24;     // channels stored in H
constexpr int NBT   = BATCH * TT;   // 8184
constexpr int FRS   = NCH * RL;     // frame stride in halfs (6336)
constexpr int PPR   = RL / 2;       // 132 pairs per row
constexpr float EPS = 1e-5f;

typedef _Float16 h2v __attribute__((ext_vector_type(2)));

__device__ inline float fdot2(unsigned a, unsigned b, float c) {
#if __has_builtin(__builtin_amdgcn_fdot2)
  return __builtin_amdgcn_fdot2(__builtin_bit_cast(h2v, a),
                                __builtin_bit_cast(h2v, b), c, false);
#else
  h2v av = __builtin_bit_cast(h2v, a), bv = __builtin_bit_cast(h2v, b);
  return fmaf((float)av[0], (float)bv[0], fmaf((float)av[1], (float)bv[1], c));
#endif
}
__device__ inline unsigned packh2(float a, float b) {
  h2v v; v[0] = (_Float16)a; v[1] = (_Float16)b;
  return __builtin_bit_cast(unsigned, v);
}
__device__ inline unsigned short f2h(float v) {
  return __builtin_bit_cast(unsigned short, (_Float16)v);
}
__device__ inline __half2 u2h(unsigned u) { return __builtin_bit_cast(__half2, u); }
__device__ inline int div132(int p) { return (p * 993) >> 17; }  // valid p<3169

// ---------------------------------------------------------------------------
// Kernel A: STFT (hann, 512-pt rfft) + l0 TD block. One workgroup per (b,t).
// DFT: bin-pair (k,256-k) split across lane k (even-n chains) and lane k+128
// (odd-n chains), 32 iters each, combined via LDS. (HBM-drain-floored.)
// ---------------------------------------------------------------------------
__global__ __launch_bounds__(256, 8) void stft_l0_kernel(
    const float* __restrict__ x,
    const float* __restrict__ W1g, const float* __restrict__ b1g,
    const float* __restrict__ W2g, const float* __restrict__ b2g,
    __half* __restrict__ H, float* __restrict__ stats0)
{
  __shared__ float  xw[512];     // windowed frame
  __shared__ __align__(16) float2 abE[128];  // ab[2j]   (even n)
  __shared__ __align__(16) float2 abO[128];  // ab[2j+1] (odd n)
  __shared__ float2 oxc[128];    // odd-lane partial sums exchange
  __shared__ float  sre[NF + 2];
  __shared__ float  sim[NF + 2];
  __shared__ float  h1[4][NF + 2];
  __shared__ float  wW1[24], wb1[4], wW2[96], wb2[8];
  __shared__ float  red[8];

  const int tid = threadIdx.x;
  const int bt  = blockIdx.x;
  const int b   = bt / TT;
  const int t   = bt - b * TT;
  const float* xp = x + (size_t)b * SLEN + (size_t)t * 256;

  if (tid < 24) wW1[tid] = W1g[tid];
  if (tid < 4)  wb1[tid] = b1g[tid];
  if (tid < 96) wW2[tid] = W2g[tid];
  if (tid < 8)  wb2[tid] = b2g[tid];

  const float STEP = 6.283185307179586f / 512.0f;
  for (int n = tid; n < 512; n += 256) {
    float sv, cv;
    sincosf(STEP * (float)n, &sv, &cv);
    xw[n] = xp[n] * (0.5f - 0.5f * cv);   // hann window
  }
  __syncthreads();

  if (tid < 128) {      // abE[j] = ab[2j]; ab[0] = 0
    const int n = 2 * tid;
    abE[tid] = (n == 0) ? make_float2(0.f, 0.f)
                        : make_float2(xw[n] + xw[512 - n], xw[n] - xw[512 - n]);
  } else {              // abO[j] = ab[2j+1]
    const int n = 2 * (tid - 128) + 1;
    abO[tid - 128] = make_float2(xw[n] + xw[512 - n], xw[n] - xw[512 - n]);
  }
  __syncthreads();

  const float x0 = xw[0], x256 = xw[256];
  {
    const int  k = tid & 127;
    const bool P = (tid >= 128);              // parity: odd-n chains
    float s1, c1;
    sincosf(STEP * (float)k, &s1, &c1);
    const float c2 = fmaf(c1,c1,-s1*s1), s2 = 2.f*c1*s1;
    const float c3 = fmaf(c2,c1,-s2*s1), s3 = fmaf(c2,s1, s2*c1);
    const float c4 = fmaf(c2,c2,-s2*s2), s4 = 2.f*c2*s2;
    const float c5 = fmaf(c4,c1,-s4*s1), s5 = fmaf(c4,s1, s4*c1);
    const float c6 = fmaf(c4,c2,-s4*s2), s6 = fmaf(c4,s2, s4*c2);
    const float c7 = fmaf(c4,c3,-s4*s3), s7 = fmaf(c4,s3, s4*c3);
    const float c8 = fmaf(c4,c4,-s4*s4), s8 = 2.f*c4*s4;
    float cA = P ? c1 : 1.f, sA = P ? s1 : 0.f;   // n0 = P
    float cB = P ? c3 : c2,  sB = P ? s3 : s2;    // n0 = P+2
    float cC = P ? c5 : c4,  sC = P ? s5 : s4;    // n0 = P+4
    float cD = P ? c7 : c6,  sD = P ? s7 : s6;    // n0 = P+6
    const float4* ab4 = P ? (const float4*)abO : (const float4*)abE;
    float re = 0.f, im = 0.f;
    for (int m = 0; m < 32; ++m) {
      const float4 q0 = ab4[2*m];
      const float4 q1 = ab4[2*m + 1];
      re = fmaf(q0.x, cA, re); im = fmaf(q0.y, sA, im);
      re = fmaf(q0.z, cB, re); im = fmaf(q0.w, sB, im);
      re = fmaf(q1.x, cC, re); im = fmaf(q1.y, sC, im);
      re = fmaf(q1.z, cD, re); im = fmaf(q1.w, sD, im);
      float t0;
      t0 = fmaf(cA, c8, -sA*s8); sA = fmaf(cA, s8, sA*c8); cA = t0;
      t0 = fmaf(cB, c8, -sB*s8); sB = fmaf(cB, s8, sB*c8); cB = t0;
      t0 = fmaf(cC, c8, -sC*s8); sC = fmaf(cC, s8, sC*c8); cC = t0;
      t0 = fmaf(cD, c8, -sD*s8); sD = fmaf(cD, s8, sD*c8); cD = t0;
    }
    if (P) oxc[k] = make_float2(re, im);

    // bin 128 contribution: lane tid handles n = tid
    float tr = 0.f, ti = 0.f;
    if (tid & 1) {
      const float v = abO[tid >> 1].y;
      ti = ((tid >> 1) & 1) ? v : -v;
    } else {
      const float v = abE[tid >> 1].x;
      tr = ((tid >> 1) & 1) ? -v : v;
    }
    #pragma unroll
    for (int off = 32; off > 0; off >>= 1) {
      tr += __shfl_down(tr, off, 64);
      ti += __shfl_down(ti, off, 64);
    }
    if ((tid & 63) == 0) { red[(tid >> 6)*2] = tr; red[(tid >> 6)*2 + 1] = ti; }
    __syncthreads();

    if (!P) {
      const float rb  = x0 + ((k & 1) ? -x256 : x256);
      const float reo = oxc[k].x, imo = oxc[k].y;
      sre[1 + k]       = rb + re + reo;
      sim[1 + k]       = -(im + imo);
      sre[1 + 256 - k] = rb + re - reo;
      sim[1 + 256 - k] = im - imo;
    }
    if (tid == 0) {
      sre[1 + 128] = x0 + x256 + red[0] + red[2] + red[4] + red[6];
      sim[1 + 128] = red[1] + red[3] + red[5] + red[7];
      sre[0] = 0.f; sim[0] = 0.f; sre[258] = 0.f; sim[258] = 0.f;
    }
  }
  __syncthreads();

  // conv1: (f,2) -> (f,4), k=3 same, relu
  for (int f = tid; f < NF; f += 256) {
    float acc[4] = {wb1[0], wb1[1], wb1[2], wb1[3]};
    #pragma unroll
    for (int i = 0; i < 3; ++i) {
      float vr = sre[f + i], vi = sim[f + i];
      #pragma unroll
      for (int c = 0; c < 4; ++c)
        acc[c] = fmaf(vr, wW1[(i*2+0)*4 + c], fmaf(vi, wW1[(i*2+1)*4 + c], acc[c]));
    }
    #pragma unroll
    for (int c = 0; c < 4; ++c) h1[c][f + 1] = fmaxf(acc[c], 0.f);
  }
  if (tid < 4) { h1[tid][0] = 0.f; h1[tid][NF + 1] = 0.f; }
  __syncthreads();

  // conv2: (f,4) -> (f,8), relu, store fp16 padded channel-major + stats
  const size_t obase = (size_t)bt * FRS;
  float ps1 = 0.f, ps2 = 0.f;
  for (int f = tid; f < NF; f += 256) {
    float acc[8];
    #pragma unroll
    for (int c = 0; c < 8; ++c) acc[c] = wb2[c];
    #pragma unroll
    for (int i = 0; i < 3; ++i)
      #pragma unroll
      for (int c4 = 0; c4 < 4; ++c4) {
        float hv = h1[c4][f + i];
        #pragma unroll
        for (int c = 0; c < 8; ++c)
          acc[c] = fmaf(hv, wW2[(i*4+c4)*8 + c], acc[c]);
      }
    #pragma unroll
    for (int c = 0; c < 8; ++c) {
      const __half hv = __float2half(fmaxf(acc[c], 0.f));
      H[obase + (size_t)c * RL + f] = hv;
      const float v = __half2float(hv);
      ps1 += v;
      ps2 = fmaf(v, v, ps2);
    }
  }
  if (tid < 56) {   // zero row pads f = 257..263 for channels 0..7
    const int c = tid / 7, f = 257 + tid - 7 * (tid / 7);
    H[obase + (size_t)c * RL + f] = __float2half(0.f);
  }
  #pragma unroll
  for (int off = 32; off > 0; off >>= 1) {
    ps1 += __shfl_down(ps1, off, 64);
    ps2 += __shfl_down(ps2, off, 64);
  }
  __syncthreads();  // red[] reused
  if ((tid & 63) == 0) { red[(tid >> 6) * 2] = ps1; red[(tid >> 6) * 2 + 1] = ps2; }
  __syncthreads();
  if (tid == 0) {
    stats0[bt * 2]     = red[0] + red[2] + red[4] + red[6];
    stats0[bt * 2 + 1] = red[1] + red[3] + red[5] + red[7];
  }
}

// ---------------------------------------------------------------------------
// Fold LN/depthwise tables into interleaved uint4 stream TI[pair] =
// {P0, P1, P2, Q0} (packed half2 words) + side planes Q1s/Q2s (causal
// boundary variants). Pair p covers padded elems (2p, 2p+1); pads = 0.
// ---------------------------------------------------------------------------
__device__ inline void fold_pair(int p, int CIN,
    const float* g, const float* bn, const float* dw,
    uint4* TI, unsigned* Q1s, unsigned* Q2s)
{
  const int c = p / PPR, fp = p - PPR * c;
  float P0[2], P1[2], P2[2], Q0[2], Q1[2], Q2[2];
  #pragma unroll
  for (int h = 0; h < 2; ++h) {
    const int f = 2 * fp + h;
    if (f < NF) {
      const int s = f * CIN + c;
      const float gv = g[s], bv = bn[s];
      const float d0 = dw[s*3], d1 = dw[s*3+1], d2 = dw[s*3+2];
      P0[h] = gv * d0; P1[h] = gv * d1; P2[h] = gv * d2;
      Q0[h] = bv * (d0 + d1 + d2); Q1[h] = bv * (d1 + d2); Q2[h] = bv * d2;
    } else {
      P0[h] = P1[h] = P2[h] = Q0[h] = Q1[h] = Q2[h] = 0.f;
    }
  }
  TI[p] = make_uint4(packh2(P0[0], P0[1]), packh2(P1[0], P1[1]),
                     packh2(P2[0], P2[1]), packh2(Q0[0], Q0[1]));
  Q1s[p] = packh2(Q1[0], Q1[1]);
  Q2s[p] = packh2(Q2[0], Q2[1]);
}

__global__ __launch_bounds__(256) void fold_all(
    const float* g1, const float* bn1, const float* dw1,
    uint4* T1, unsigned* Q1a, unsigned* Q2a,
    const float* g2, const float* bn2, const float* dw2,
    uint4* T2, unsigned* Q1b, unsigned* Q2b,
    const float* g3, const float* bn3, const float* dw3,
    uint4* T3, unsigned* Q1c, unsigned* Q2c)
{
  int p = blockIdx.x * 256 + threadIdx.x;
  if (p < 8 * PPR) { fold_pair(p, 8, g1, bn1, dw1, T1, Q1a, Q2a); return; }
  p -= 8 * PPR;
  if (p < 16 * PPR) { fold_pair(p, 16, g2, bn2, dw2, T2, Q1b, Q2b); return; }
  p -= 16 * PPR;
  if (p < 24 * PPR) fold_pair(p, 24, g3, bn3, dw3, T3, Q1c, Q2c);
}

// ---------------------------------------------------------------------------
// Layer kernel, one block per (b,t). Stage A: pair-granular with interleaved
// uint4 table load (4 load instrs/pair vs 7), padded rows (no boundary
// cases, mul-shift addressing); packed fp16 math; dot2 convs.
// ---------------------------------------------------------------------------
template<int CIN, bool HEAD>
__global__ __launch_bounds__(256, 8) void layer_bt(
    const __half* __restrict__ H, __half* __restrict__ Hout,
    const float* __restrict__ st0, const float* __restrict__ st1,
    const float* __restrict__ st2, float* __restrict__ stats_out,
    const uint4* __restrict__ TI,
    const unsigned* __restrict__ Q1s, const unsigned* __restrict__ Q2s,
    const float* __restrict__ W1g, const float* __restrict__ b1g,
    const float* __restrict__ W2g, const float* __restrict__ b2g,
    const float* __restrict__ fc1W, const float* __restrict__ fc1b,
    const float* __restrict__ fc2W, const float* __restrict__ fc2b,
    float* __restrict__ out)
{
  constexpr int NEL   = CIN * NF;               // real LN element count
  constexpr int NPAIR = CIN * PPR;              // 1056 / 2112 / 3168
  constexpr int NJ    = (NPAIR + 255) / 256;    // 5 / 9 / 13
  constexpr int PC1   = CIN + 2;                // 10 / 18 / 26 halfs (odd words)
  constexpr int PC2   = 10;                     // h1 row: 8 + 2 pad
  constexpr int NQ1   = CIN / 2;                // channel pairs

  __shared__ unsigned short y_t[265 * PC1];     // [row f+1][c]; rows 258+ = pads
  __shared__ unsigned short h1_t[259 * PC2];    // [row f+1][c8]
  __shared__ unsigned w1p[3 * NQ1 * 8];         // half2-packed conv1 weights
  __shared__ unsigned w2p[96];                  // half2-packed conv2 weights
  __shared__ float wb1[8], wb2[8];
  __shared__ float red[8];
  __shared__ unsigned wfc1p[HEAD ? 48 : 1];     // half2-packed fc1 weights

  const int tid = threadIdx.x;
  const int bt  = blockIdx.x;
  const int b   = bt / TT;
  const int t   = bt - b * TT;

  // ---- weight packing + halo init ----
  for (int idx = tid; idx < 3 * NQ1 * 8; idx += 256) {
    const int o = idx & 7, q = (idx >> 3) % NQ1, i = idx / (NQ1 * 8);
    w1p[idx] = packh2(W1g[(i*CIN + 2*q)*8 + o], W1g[(i*CIN + 2*q + 1)*8 + o]);
  }
  if (tid < 96) {
    const int o = tid & 7, q = (tid >> 3) & 3, i = tid >> 5;
    w2p[tid] = packh2(W2g[(i*8 + 2*q)*8 + o], W2g[(i*8 + 2*q + 1)*8 + o]);
  }
  if (tid < 8) { wb1[tid] = b1g[tid]; wb2[tid] = b2g[tid]; }
  if (tid < PC1) y_t[tid] = 0;                      // row 0 halo (f = -1)
  if (tid < PC2) { h1_t[tid] = 0; h1_t[258*PC2 + tid] = 0; }
  if constexpr (HEAD) {
    if (tid < 48) {
      const int q = tid & 15, i = tid >> 4;
      wfc1p[tid] = packh2(fc1W[i*32 + 2*q], fc1W[i*32 + 2*q + 1]);
    }
  }

  // ---- per-frame LN stats from producer partials ----
  float mu0 = 0.f, rs0 = 0.f, mu1 = 0.f, rs1 = 0.f, mu2, rs2;
  {
    const float inv = 1.0f / (float)NEL;
    float s1 = st0[bt*2], s2v = st0[bt*2+1];
    if constexpr (CIN >= 16) { s1 += st1[bt*2]; s2v += st1[bt*2+1]; }
    if constexpr (CIN >= 24) { s1 += st2[bt*2]; s2v += st2[bt*2+1]; }
    mu2 = s1 * inv; rs2 = rsqrtf(s2v * inv - mu2*mu2 + EPS);
    if (t >= 1) {
      const int fb = bt - 1;
      float a = st0[fb*2], c = st0[fb*2+1];
      if constexpr (CIN >= 16) { a += st1[fb*2]; c += st1[fb*2+1]; }
      if constexpr (CIN >= 24) { a += st2[fb*2]; c += st2[fb*2+1]; }
      mu1 = a * inv; rs1 = rsqrtf(c * inv - mu1*mu1 + EPS);
    }
    if (t >= 2) {
      const int fb = bt - 2;
      float a = st0[fb*2], c = st0[fb*2+1];
      if constexpr (CIN >= 16) { a += st1[fb*2]; c += st1[fb*2+1]; }
      if constexpr (CIN >= 24) { a += st2[fb*2]; c += st2[fb*2+1]; }
      mu0 = a * inv; rs0 = rsqrtf(c * inv - mu0*mu0 + EPS);
    }
  }
  const __half2 rs0h = __float2half2_rn(rs0);
  const __half2 rs1h = __float2half2_rn(rs1);
  const __half2 rs2h = __float2half2_rn(rs2);
  const __half2 nm0h = __float2half2_rn(-mu0);
  const __half2 nm1h = __float2half2_rn(-mu1);
  const __half2 nm2h = __float2half2_rn(-mu2);

  const int base = b * TT;
  const unsigned* F2 = (const unsigned*)(H + (size_t)bt * FRS);
  const unsigned* F1 = (const unsigned*)(H + (size_t)max(bt - 1, base) * FRS);
  const unsigned* F0 = (const unsigned*)(H + (size_t)max(bt - 2, base) * FRS);
  const bool useSide = (t < 2);
  const unsigned* Qside = (t == 1) ? Q1s : Q2s;

  // ---- stage A: packed-fp16 LN + causal depthwise -> y_t (transposed) ----
  #pragma unroll
  for (int j = 0; j < NJ; ++j) {
    const int p = tid + 256 * j;
    const bool act = (j < NJ - 1) || (p < NPAIR);
    if (act) {
      const uint4 T = TI[p];
      unsigned qw = T.w;
      if (useSide) qw = Qside[p];
      const unsigned x0 = F0[p], x1 = F1[p], x2 = F2[p];
      const __half2 rp0 = __hmul2(rs0h, u2h(T.x));
      const __half2 rp1 = __hmul2(rs1h, u2h(T.y));
      const __half2 rp2 = __hmul2(rs2h, u2h(T.z));
      __half2 acc = __hfma2(nm0h, rp0, u2h(qw));
      acc = __hfma2(nm1h, rp1, acc);
      acc = __hfma2(nm2h, rp2, acc);
      acc = __hfma2(u2h(x0), rp0, acc);
      acc = __hfma2(u2h(x1), rp1, acc);
      acc = __hfma2(u2h(x2), rp2, acc);
      const unsigned r = __builtin_bit_cast(unsigned, acc);
      const int c = div132(p);
      const int f = 2 * (p - PPR * c);
      const int a = (f + 1) * PC1 + c;
      y_t[a]       = (unsigned short)(r & 0xffffu);
      y_t[a + PC1] = (unsigned short)(r >> 16);
    }
  }
  __syncthreads();

  // ---- stage B: conv1 (f,CIN)->(f,8) via dot2, relu ----
  {
    const int f = tid;  // output f = 0..255; reads y_t rows f..f+2
    float acc[8];
    #pragma unroll
    for (int c = 0; c < 8; ++c) acc[c] = wb1[c];
    const unsigned* yw = (const unsigned*)y_t;
    #pragma unroll
    for (int i = 0; i < 3; ++i) {
      const unsigned* row = yw + (f + i) * (PC1 / 2);
      for (int q = 0; q < NQ1; ++q) {
        const unsigned yv = row[q];
        #pragma unroll
        for (int c = 0; c < 8; ++c)
          acc[c] = fdot2(yv, w1p[(i * NQ1 + q) * 8 + c], acc[c]);
      }
    }
    unsigned* hw = (unsigned*)h1_t + (f + 1) * (PC2 / 2);
    #pragma unroll
    for (int k = 0; k < 4; ++k)
      hw[k] = packh2(fmaxf(acc[2*k], 0.f), fmaxf(acc[2*k+1], 0.f));
  }
  if (tid < 8) {  // sidecar: f=256 (row 257), out-channel = tid
    float a = wb1[tid];
    const unsigned* yw = (const unsigned*)y_t;
    #pragma unroll
    for (int i = 0; i < 3; ++i) {
      const unsigned* row = yw + (256 + i) * (PC1 / 2);
      for (int q = 0; q < NQ1; ++q)
        a = fdot2(row[q], w1p[(i * NQ1 + q) * 8 + tid], a);
    }
    h1_t[257 * PC2 + tid] = f2h(fmaxf(a, 0.f));
  }
  __syncthreads();

  // ---- stage C: conv2 (f,8)->(f,8) via dot2, relu ----
  float ps1 = 0.f, ps2 = 0.f;
  {
    const int f = tid;
    float o2[8];
    #pragma unroll
    for (int c = 0; c < 8; ++c) o2[c] = wb2[c];
    const unsigned* hw = (const unsigned*)h1_t;
    #pragma unroll
    for (int i = 0; i < 3; ++i) {
      const unsigned* row = hw + (f + i) * (PC2 / 2);
      #pragma unroll
      for (int q = 0; q < 4; ++q) {
        const unsigned hv = row[q];
        #pragma unroll
        for (int c = 0; c < 8; ++c)
          o2[c] = fdot2(hv, w2p[(i*4 + q)*8 + c], o2[c]);
      }
    }
    if constexpr (!HEAD) {
      const size_t ob = (size_t)bt * FRS + (size_t)CIN * RL;
      #pragma unroll
      for (int c = 0; c < 8; ++c) {
        const __half hv = __float2half(fmaxf(o2[c], 0.f));
        Hout[ob + (size_t)c * RL + f] = hv;
        const float v = __half2float(hv);
        ps1 += v;
        ps2 = fmaf(v, v, ps2);
      }
    } else {
      unsigned* ow = (unsigned*)y_t + f * (PC1 / 2);  // out2_t row f (y_t dead)
      #pragma unroll
      for (int k = 0; k < 4; ++k)
        ow[k] = packh2(fmaxf(o2[2*k], 0.f), fmaxf(o2[2*k+1], 0.f));
    }
  }
  if (tid >= 8 && tid < 16) {  // sidecar: f=256, ch = tid-8
    const int c8 = tid - 8;
    float a = wb2[c8];
    const unsigned* hw = (const unsigned*)h1_t;
    #pragma unroll
    for (int i = 0; i < 3; ++i) {
      const unsigned* row = hw + (256 + i) * (PC2 / 2);
      #pragma unroll
      for (int q = 0; q < 4; ++q)
        a = fdot2(row[q], w2p[(i*4 + q)*8 + c8], a);
    }
    if constexpr (!HEAD) {
      const size_t ob = (size_t)bt * FRS + (size_t)CIN * RL;
      const __half hv = __float2half(fmaxf(a, 0.f));
      Hout[ob + (size_t)c8 * RL + 256] = hv;
      const float v = __half2float(hv);
      ps1 += v;
      ps2 = fmaf(v, v, ps2);
    } else {
      y_t[256 * PC1 + c8] = f2h(fmaxf(a, 0.f));
    }
  }
  if constexpr (!HEAD) {
    if (tid >= 64 && tid < 120) {   // zero output row pads f = 257..263
      const size_t ob = (size_t)bt * FRS + (size_t)CIN * RL;
      const int i2 = tid - 64;
      const int c = i2 / 7, f = 257 + i2 - 7 * (i2 / 7);
      Hout[ob + (size_t)c * RL + f] = __float2half(0.f);
    }
  }

  if constexpr (!HEAD) {
    #pragma unroll
    for (int off = 32; off > 0; off >>= 1) {
      ps1 += __shfl_down(ps1, off, 64);
      ps2 += __shfl_down(ps2, off, 64);
    }
    if ((tid & 63) == 0) { red[(tid >> 6)*2] = ps1; red[(tid >> 6)*2+1] = ps2; }
    __syncthreads();
    if (tid == 0) {
      stats_out[bt*2]     = red[0] + red[2] + red[4] + red[6];
      stats_out[bt*2 + 1] = red[1] + red[3] + red[5] + red[7];
    }
  } else {
    __syncthreads();  // out2_t complete
    // ---- stage D: fc1 (valid k=3, 32ch) + relu + fc2 + sigmoid ----
    float part = 0.f;
    if (tid < NF - 2) {
      const unsigned short* xgu = (const unsigned short*)F2;  // frame t, L1-warm
      float acc = fc1b[0];
      #pragma unroll
      for (int i = 0; i < 3; ++i) {
        const int pos = tid + i;
        for (int q = 0; q < 12; ++q) {   // raw-input channel pairs
          const unsigned lo = xgu[(2*q) * RL + pos];
          const unsigned hi = xgu[(2*q + 1) * RL + pos];
          acc = fdot2(lo | (hi << 16), wfc1p[i*16 + q], acc);
        }
        const unsigned* orow = (const unsigned*)y_t + pos * (PC1 / 2);
        #pragma unroll
        for (int q = 0; q < 4; ++q)      // this layer's 8 output channels
          acc = fdot2(orow[q], wfc1p[i*16 + 12 + q], acc);
      }
      part = fmaxf(acc, 0.f) * fc2W[tid];
    }
    #pragma unroll
    for (int off = 32; off > 0; off >>= 1) part += __shfl_down(part, off, 64);
    if ((tid & 63) == 0) red[tid >> 6] = part;
    __syncthreads();
    if (tid == 0) {
      const float tot = red[0] + red[1] + red[2] + red[3] + fc2b[0];
      out[bt] = 1.0f / (1.0f + expf(-tot));
    }
  }
}

}  // namespace

extern "C" void kernel_launch(void* const* d_in, const int* in_sizes, int n_in,
                              void* d_out, int out_size, void* d_ws, size_t ws_size,
                              hipStream_t stream) {
  (void)in_sizes; (void)n_in; (void)out_size; (void)ws_size;
  const float* x = (const float*)d_in[0];
  float* out = (float*)d_out;
  char*  wsb = (char*)d_ws;

  // Workspace layout (bytes; all chunks 16B-aligned)
  __half* H = (__half*)wsb;                          // NBT*FRS halfs ~103.7 MB
  char* p = wsb + (size_t)NBT * FRS * sizeof(__half);
  float* st0 = (float*)p; p += 2 * NBT * sizeof(float);
  float* st1 = (float*)p; p += 2 * NBT * sizeof(float);
  float* st2 = (float*)p; p += 2 * NBT * sizeof(float);
  uint4*    T1  = (uint4*)p;    p += (size_t)(8  * PPR) * 16;
  unsigned* Q1a = (unsigned*)p; p += (size_t)(8  * PPR) * 4;
  unsigned* Q2a = (unsigned*)p; p += (size_t)(8  * PPR) * 4;
  uint4*    T2  = (uint4*)p;    p += (size_t)(16 * PPR) * 16;
  unsigned* Q1b = (unsigned*)p; p += (size_t)(16 * PPR) * 4;
  unsigned* Q2b = (unsigned*)p; p += (size_t)(16 * PPR) * 4;
  uint4*    T3  = (uint4*)p;    p += (size_t)(24 * PPR) * 16;
  unsigned* Q1c = (unsigned*)p; p += (size_t)(24 * PPR) * 4;
  unsigned* Q2c = (unsigned*)p;

  dim3 blk(256);

  fold_all<<<dim3((48 * PPR + 255) / 256), blk, 0, stream>>>(
      (const float*)d_in[5],  (const float*)d_in[6],  (const float*)d_in[7],
      T1, Q1a, Q2a,
      (const float*)d_in[12], (const float*)d_in[13], (const float*)d_in[14],
      T2, Q1b, Q2b,
      (const float*)d_in[19], (const float*)d_in[20], (const float*)d_in[21],
      T3, Q1c, Q2c);

  stft_l0_kernel<<<dim3(NBT), blk, 0, stream>>>(
      x, (const float*)d_in[1], (const float*)d_in[2],
      (const float*)d_in[3], (const float*)d_in[4], H, st0);

  layer_bt<8, false><<<dim3(NBT), blk, 0, stream>>>(
      H, H, st0, nullptr, nullptr, st1, T1, Q1a, Q2a,
      (const float*)d_in[8], (const float*)d_in[9],
      (const float*)d_in[10], (const float*)d_in[11],
      nullptr, nullptr, nullptr, nullptr, nullptr);

  layer_bt<16, false><<<dim3(NBT), blk, 0, stream>>>(
      H, H, st0, st1, nullptr, st2, T2, Q1b, Q2b,
      (const float*)d_in[15], (const float*)d_in[16],
      (const float*)d_in[17], (const float*)d_in[18],
      nullptr, nullptr, nullptr, nullptr, nullptr);

  layer_bt<24, true><<<dim3(NBT), blk, 0, stream>>>(
      H, nullptr, st0, st1, st2, nullptr, T3, Q1c, Q2c,
      (const float*)d_in[22], (const float*)d_in[23],
      (const float*)d_in[24], (const float*)d_in[25],
      (const float*)d_in[26], (const float*)d_in[27],
      (const float*)d_in[28], (const float*)d_in[29],
      out);
}

// Round 12
// 402.619 us; speedup vs baseline: 1.0716x; 1.0716x over previous
//
#include <hip/hip_runtime.h>
#include <hip/hip_fp16.h>

namespace {

constexpr int BATCH = 8;
constexpr int SLEN  = 262144;
constexpr int TT    = 1023;   // (262144-512)/256 + 1
constexpr int NF    = 257;    // rfft bins
constexpr int NCH   = 24;     // channels stored in H
constexpr int NBT   = BATCH * TT;   // 8184
constexpr int FRS   = NCH * NF;     // frame stride in halfs (6168)
constexpr float EPS = 1e-5f;

typedef _Float16 h2v __attribute__((ext_vector_type(2)));

__device__ inline float fdot2(unsigned a, unsigned b, float c) {
#if __has_builtin(__builtin_amdgcn_fdot2)
  return __builtin_amdgcn_fdot2(__builtin_bit_cast(h2v, a),
                                __builtin_bit_cast(h2v, b), c, false);
#else
  h2v av = __builtin_bit_cast(h2v, a), bv = __builtin_bit_cast(h2v, b);
  return fmaf((float)av[0], (float)bv[0], fmaf((float)av[1], (float)bv[1], c));
#endif
}
__device__ inline unsigned packh2(float a, float b) {
  h2v v; v[0] = (_Float16)a; v[1] = (_Float16)b;
  return __builtin_bit_cast(unsigned, v);
}
__device__ inline unsigned short f2h(float v) {
  return __builtin_bit_cast(unsigned short, (_Float16)v);
}
__device__ inline __half2 u2h(unsigned u) { return __builtin_bit_cast(__half2, u); }
__device__ inline int div257(int e) { return (e * 65282) >> 24; }  // valid e<6168

// ---------------------------------------------------------------------------
// Kernel A: STFT (hann, 512-pt rfft) + l0 TD block. One workgroup per (b,t).
// DFT: bin-pair (k,256-k) split across lane k (even-n chains) and lane k+128
// (odd-n chains), 32 iters each, combined via LDS. (HBM-drain-floored.)
// ---------------------------------------------------------------------------
__global__ __launch_bounds__(256, 8) void stft_l0_kernel(
    const float* __restrict__ x,
    const float* __restrict__ W1g, const float* __restrict__ b1g,
    const float* __restrict__ W2g, const float* __restrict__ b2g,
    __half* __restrict__ H, float* __restrict__ stats0)
{
  __shared__ float  xw[512];     // windowed frame
  __shared__ __align__(16) float2 abE[128];  // ab[2j]   (even n)
  __shared__ __align__(16) float2 abO[128];  // ab[2j+1] (odd n)
  __shared__ float2 oxc[128];    // odd-lane partial sums exchange
  __shared__ float  sre[NF + 2];
  __shared__ float  sim[NF + 2];
  __shared__ float  h1[4][NF + 2];
  __shared__ float  wW1[24], wb1[4], wW2[96], wb2[8];
  __shared__ float  red[8];

  const int tid = threadIdx.x;
  const int bt  = blockIdx.x;
  const int b   = bt / TT;
  const int t   = bt - b * TT;
  const float* xp = x + (size_t)b * SLEN + (size_t)t * 256;

  if (tid < 24) wW1[tid] = W1g[tid];
  if (tid < 4)  wb1[tid] = b1g[tid];
  if (tid < 96) wW2[tid] = W2g[tid];
  if (tid < 8)  wb2[tid] = b2g[tid];

  const float STEP = 6.283185307179586f / 512.0f;
  for (int n = tid; n < 512; n += 256) {
    float sv, cv;
    sincosf(STEP * (float)n, &sv, &cv);
    xw[n] = xp[n] * (0.5f - 0.5f * cv);   // hann window
  }
  __syncthreads();

  if (tid < 128) {      // abE[j] = ab[2j]; ab[0] = 0
    const int n = 2 * tid;
    abE[tid] = (n == 0) ? make_float2(0.f, 0.f)
                        : make_float2(xw[n] + xw[512 - n], xw[n] - xw[512 - n]);
  } else {              // abO[j] = ab[2j+1]
    const int n = 2 * (tid - 128) + 1;
    abO[tid - 128] = make_float2(xw[n] + xw[512 - n], xw[n] - xw[512 - n]);
  }
  __syncthreads();

  const float x0 = xw[0], x256 = xw[256];
  {
    const int  k = tid & 127;
    const bool P = (tid >= 128);              // parity: odd-n chains
    float s1, c1;
    sincosf(STEP * (float)k, &s1, &c1);
    const float c2 = fmaf(c1,c1,-s1*s1), s2 = 2.f*c1*s1;
    const float c3 = fmaf(c2,c1,-s2*s1), s3 = fmaf(c2,s1, s2*c1);
    const float c4 = fmaf(c2,c2,-s2*s2), s4 = 2.f*c2*s2;
    const float c5 = fmaf(c4,c1,-s4*s1), s5 = fmaf(c4,s1, s4*c1);
    const float c6 = fmaf(c4,c2,-s4*s2), s6 = fmaf(c4,s2, s4*c2);
    const float c7 = fmaf(c4,c3,-s4*s3), s7 = fmaf(c4,s3, s4*c3);
    const float c8 = fmaf(c4,c4,-s4*s4), s8 = 2.f*c4*s4;
    float cA = P ? c1 : 1.f, sA = P ? s1 : 0.f;   // n0 = P
    float cB = P ? c3 : c2,  sB = P ? s3 : s2;    // n0 = P+2
    float cC = P ? c5 : c4,  sC = P ? s5 : s4;    // n0 = P+4
    float cD = P ? c7 : c6,  sD = P ? s7 : s6;    // n0 = P+6
    const float4* ab4 = P ? (const float4*)abO : (const float4*)abE;
    float re = 0.f, im = 0.f;
    for (int m = 0; m < 32; ++m) {
      const float4 q0 = ab4[2*m];
      const float4 q1 = ab4[2*m + 1];
      re = fmaf(q0.x, cA, re); im = fmaf(q0.y, sA, im);
      re = fmaf(q0.z, cB, re); im = fmaf(q0.w, sB, im);
      re = fmaf(q1.x, cC, re); im = fmaf(q1.y, sC, im);
      re = fmaf(q1.z, cD, re); im = fmaf(q1.w, sD, im);
      float t0;
      t0 = fmaf(cA, c8, -sA*s8); sA = fmaf(cA, s8, sA*c8); cA = t0;
      t0 = fmaf(cB, c8, -sB*s8); sB = fmaf(cB, s8, sB*c8); cB = t0;
      t0 = fmaf(cC, c8, -sC*s8); sC = fmaf(cC, s8, sC*c8); cC = t0;
      t0 = fmaf(cD, c8, -sD*s8); sD = fmaf(cD, s8, sD*c8); cD = t0;
    }
    if (P) oxc[k] = make_float2(re, im);

    // bin 128 contribution: lane tid handles n = tid
    float tr = 0.f, ti = 0.f;
    if (tid & 1) {
      const float v = abO[tid >> 1].y;
      ti = ((tid >> 1) & 1) ? v : -v;
    } else {
      const float v = abE[tid >> 1].x;
      tr = ((tid >> 1) & 1) ? -v : v;
    }
    #pragma unroll
    for (int off = 32; off > 0; off >>= 1) {
      tr += __shfl_down(tr, off, 64);
      ti += __shfl_down(ti, off, 64);
    }
    if ((tid & 63) == 0) { red[(tid >> 6)*2] = tr; red[(tid >> 6)*2 + 1] = ti; }
    __syncthreads();

    if (!P) {
      const float rb  = x0 + ((k & 1) ? -x256 : x256);
      const float reo = oxc[k].x, imo = oxc[k].y;
      sre[1 + k]       = rb + re + reo;
      sim[1 + k]       = -(im + imo);
      sre[1 + 256 - k] = rb + re - reo;
      sim[1 + 256 - k] = im - imo;
    }
    if (tid == 0) {
      sre[1 + 128] = x0 + x256 + red[0] + red[2] + red[4] + red[6];
      sim[1 + 128] = red[1] + red[3] + red[5] + red[7];
      sre[0] = 0.f; sim[0] = 0.f; sre[258] = 0.f; sim[258] = 0.f;
    }
  }
  __syncthreads();

  // conv1: (f,2) -> (f,4), k=3 same, relu
  for (int f = tid; f < NF; f += 256) {
    float acc[4] = {wb1[0], wb1[1], wb1[2], wb1[3]};
    #pragma unroll
    for (int i = 0; i < 3; ++i) {
      float vr = sre[f + i], vi = sim[f + i];
      #pragma unroll
      for (int c = 0; c < 4; ++c)
        acc[c] = fmaf(vr, wW1[(i*2+0)*4 + c], fmaf(vi, wW1[(i*2+1)*4 + c], acc[c]));
    }
    #pragma unroll
    for (int c = 0; c < 4; ++c) h1[c][f + 1] = fmaxf(acc[c], 0.f);
  }
  if (tid < 4) { h1[tid][0] = 0.f; h1[tid][NF + 1] = 0.f; }
  __syncthreads();

  // conv2: (f,4) -> (f,8), relu, store fp16 channel-major + stats (rounded)
  const size_t obase = (size_t)bt * FRS;
  float ps1 = 0.f, ps2 = 0.f;
  for (int f = tid; f < NF; f += 256) {
    float acc[8];
    #pragma unroll
    for (int c = 0; c < 8; ++c) acc[c] = wb2[c];
    #pragma unroll
    for (int i = 0; i < 3; ++i)
      #pragma unroll
      for (int c4 = 0; c4 < 4; ++c4) {
        float hv = h1[c4][f + i];
        #pragma unroll
        for (int c = 0; c < 8; ++c)
          acc[c] = fmaf(hv, wW2[(i*4+c4)*8 + c], acc[c]);
      }
    #pragma unroll
    for (int c = 0; c < 8; ++c) {
      const __half hv = __float2half(fmaxf(acc[c], 0.f));
      H[obase + (size_t)c * NF + f] = hv;
      const float v = __half2float(hv);
      ps1 += v;
      ps2 = fmaf(v, v, ps2);
    }
  }
  #pragma unroll
  for (int off = 32; off > 0; off >>= 1) {
    ps1 += __shfl_down(ps1, off, 64);
    ps2 += __shfl_down(ps2, off, 64);
  }
  __syncthreads();  // red[] reused
  if ((tid & 63) == 0) { red[(tid >> 6) * 2] = ps1; red[(tid >> 6) * 2 + 1] = ps2; }
  __syncthreads();
  if (tid == 0) {
    stats0[bt * 2]     = red[0] + red[2] + red[4] + red[6];
    stats0[bt * 2 + 1] = red[1] + red[3] + red[5] + red[7];
  }
}

// ---------------------------------------------------------------------------
// Fold all three LN/depthwise tables -> fp16 planes, channel-major [c][f].
// ---------------------------------------------------------------------------
__device__ inline void fold_one(int idx, int CIN,
    const float* g, const float* bn, const float* dw, __half* dst, int NEL) {
  const int c = div257(idx), f = idx - c * 257;
  const int s = f * CIN + c;
  const float gv = g[s], bv = bn[s];
  const float d0 = dw[s*3], d1 = dw[s*3+1], d2 = dw[s*3+2];
  dst[idx]         = __float2half(gv * d0);
  dst[NEL + idx]   = __float2half(gv * d1);
  dst[2*NEL + idx] = __float2half(gv * d2);
  dst[3*NEL + idx] = __float2half(bv * (d0 + d1 + d2));
  dst[4*NEL + idx] = __float2half(bv * (d1 + d2));
  dst[5*NEL + idx] = __float2half(bv * d2);
}

__global__ __launch_bounds__(256) void fold_all(
    const float* g1, const float* bn1, const float* dw1, __half* t1,
    const float* g2, const float* bn2, const float* dw2, __half* t2,
    const float* g3, const float* bn3, const float* dw3, __half* t3)
{
  int idx = blockIdx.x * 256 + threadIdx.x;
  if (idx < 8*257) { fold_one(idx, 8, g1, bn1, dw1, t1, 8*257); return; }
  idx -= 8*257;
  if (idx < 16*257) { fold_one(idx, 16, g2, bn2, dw2, t2, 16*257); return; }
  idx -= 16*257;
  if (idx < 24*257) fold_one(idx, 24, g3, bn3, dw3, t3, 24*257);
}

// ---------------------------------------------------------------------------
// Layer kernel, one block per (b,t). Round-6 structure (half2 loads, simple
// y_t addressing, head fc1 from L1-warm global, 8 blocks/CU) with stage-A
// math in packed fp16 (rp = rs*P folded; bias via -mu*rp terms).
// ---------------------------------------------------------------------------
template<int CIN, bool HEAD>
__global__ __launch_bounds__(256, 8) void layer_bt(
    const __half* __restrict__ H, __half* __restrict__ Hout,
    const float* __restrict__ st0, const float* __restrict__ st1,
    const float* __restrict__ st2, float* __restrict__ stats_out,
    const __half* __restrict__ tbl,
    const float* __restrict__ W1g, const float* __restrict__ b1g,
    const float* __restrict__ W2g, const float* __restrict__ b2g,
    const float* __restrict__ fc1W, const float* __restrict__ fc1b,
    const float* __restrict__ fc2W, const float* __restrict__ fc2b,
    float* __restrict__ out)
{
  constexpr int NEL   = CIN * NF;               // 2056 / 4112 / 6168
  constexpr int NP2   = NEL / 2;
  constexpr int NPER2 = (NP2 + 255) / 256;      // 5 / 9 / 13
  constexpr int TAIL2 = NP2 - 256 * (NPER2 - 1);
  constexpr int PC1   = CIN + 2;                // 10 / 18 / 26 halfs (odd words)
  constexpr int PC2   = 10;                     // h1 row: 8 + 2 pad
  constexpr int NQ1   = CIN / 2;                // channel pairs

  __shared__ unsigned short y_t[259 * PC1];     // [row f+1][c]; reused as out2_t
  __shared__ unsigned short h1_t[259 * PC2];    // [row f+1][c8]
  __shared__ unsigned w1p[3 * NQ1 * 8];         // half2-packed conv1 weights
  __shared__ unsigned w2p[96];                  // half2-packed conv2 weights
  __shared__ float wb1[8], wb2[8];
  __shared__ float red[8];
  __shared__ unsigned wfc1p[HEAD ? 48 : 1];     // half2-packed fc1 weights

  const int tid = threadIdx.x;
  const int bt  = blockIdx.x;
  const int b   = bt / TT;
  const int t   = bt - b * TT;

  // ---- weight packing + halo init ----
  for (int idx = tid; idx < 3 * NQ1 * 8; idx += 256) {
    const int o = idx & 7, q = (idx >> 3) % NQ1, i = idx / (NQ1 * 8);
    w1p[idx] = packh2(W1g[(i*CIN + 2*q)*8 + o], W1g[(i*CIN + 2*q + 1)*8 + o]);
  }
  if (tid < 96) {
    const int o = tid & 7, q = (tid >> 3) & 3, i = tid >> 5;
    w2p[tid] = packh2(W2g[(i*8 + 2*q)*8 + o], W2g[(i*8 + 2*q + 1)*8 + o]);
  }
  if (tid < 8) { wb1[tid] = b1g[tid]; wb2[tid] = b2g[tid]; }
  if (tid < PC1) { y_t[tid] = 0; y_t[258*PC1 + tid] = 0; }
  if (tid < PC2) { h1_t[tid] = 0; h1_t[258*PC2 + tid] = 0; }
  if constexpr (HEAD) {
    if (tid < 48) {
      const int q = tid & 15, i = tid >> 4;
      wfc1p[tid] = packh2(fc1W[i*32 + 2*q], fc1W[i*32 + 2*q + 1]);
    }
  }

  // ---- per-frame LN stats from producer partials ----
  float mu0 = 0.f, rs0 = 0.f, mu1 = 0.f, rs1 = 0.f, mu2, rs2;
  {
    const float inv = 1.0f / (float)NEL;
    float s1 = st0[bt*2], s2v = st0[bt*2+1];
    if constexpr (CIN >= 16) { s1 += st1[bt*2]; s2v += st1[bt*2+1]; }
    if constexpr (CIN >= 24) { s1 += st2[bt*2]; s2v += st2[bt*2+1]; }
    mu2 = s1 * inv; rs2 = rsqrtf(s2v * inv - mu2*mu2 + EPS);
    if (t >= 1) {
      const int fb = bt - 1;
      float a = st0[fb*2], c = st0[fb*2+1];
      if constexpr (CIN >= 16) { a += st1[fb*2]; c += st1[fb*2+1]; }
      if constexpr (CIN >= 24) { a += st2[fb*2]; c += st2[fb*2+1]; }
      mu1 = a * inv; rs1 = rsqrtf(c * inv - mu1*mu1 + EPS);
    }
    if (t >= 2) {
      const int fb = bt - 2;
      float a = st0[fb*2], c = st0[fb*2+1];
      if constexpr (CIN >= 16) { a += st1[fb*2]; c += st1[fb*2+1]; }
      if constexpr (CIN >= 24) { a += st2[fb*2]; c += st2[fb*2+1]; }
      mu0 = a * inv; rs0 = rsqrtf(c * inv - mu0*mu0 + EPS);
    }
  }
  const __half2 rs0h = __float2half2_rn(rs0);
  const __half2 rs1h = __float2half2_rn(rs1);
  const __half2 rs2h = __float2half2_rn(rs2);
  const __half2 nm0h = __float2half2_rn(-mu0);
  const __half2 nm1h = __float2half2_rn(-mu1);
  const __half2 nm2h = __float2half2_rn(-mu2);

  const int base = b * TT;
  const unsigned* F2 = (const unsigned*)(H + (size_t)bt * FRS);
  const unsigned* F1 = (const unsigned*)(H + (size_t)max(bt - 1, base) * FRS);
  const unsigned* F0 = (const unsigned*)(H + (size_t)max(bt - 2, base) * FRS);
  const unsigned* P0 = (const unsigned*)tbl;
  const unsigned* P1 = (const unsigned*)(tbl + NEL);
  const unsigned* P2 = (const unsigned*)(tbl + 2 * NEL);
  const int qsel = (t >= 2) ? 0 : (t == 1 ? 1 : 2);
  const unsigned* Qp = (const unsigned*)(tbl + (3 + qsel) * NEL);

  // ---- stage A: packed-fp16 LN + causal depthwise -> y_t (transposed) ----
  #pragma unroll
  for (int j = 0; j < NPER2; ++j) {
    const bool act = (j < NPER2 - 1) || (tid < TAIL2);
    if (act) {
      const int p  = tid + 256 * j;
      const int e0 = 2 * p;
      const int c0 = div257(e0);
      const int fi = e0 - c0 * 257;
      const __half2 rp0 = __hmul2(rs0h, u2h(P0[p]));
      const __half2 rp1 = __hmul2(rs1h, u2h(P1[p]));
      const __half2 rp2 = __hmul2(rs2h, u2h(P2[p]));
      __half2 acc = __hfma2(nm0h, rp0, u2h(Qp[p]));
      acc = __hfma2(nm1h, rp1, acc);
      acc = __hfma2(nm2h, rp2, acc);
      acc = __hfma2(u2h(F0[p]), rp0, acc);
      acc = __hfma2(u2h(F1[p]), rp1, acc);
      acc = __hfma2(u2h(F2[p]), rp2, acc);
      const unsigned r = __builtin_bit_cast(unsigned, acc);
      const int a1 = (fi + 1) * PC1 + c0;
      y_t[a1] = (unsigned short)(r & 0xffffu);
      const int a2 = (fi == 256) ? (PC1 + c0 + 1) : (a1 + PC1);
      y_t[a2] = (unsigned short)(r >> 16);
    }
  }
  __syncthreads();

  // ---- stage B: conv1 (f,CIN)->(f,8) via dot2, relu ----
  {
    const int f = tid;  // output f = 0..255; reads y_t rows f..f+2
    float acc[8];
    #pragma unroll
    for (int c = 0; c < 8; ++c) acc[c] = wb1[c];
    const unsigned* yw = (const unsigned*)y_t;
    #pragma unroll
    for (int i = 0; i < 3; ++i) {
      const unsigned* row = yw + (f + i) * (PC1 / 2);
      for (int q = 0; q < NQ1; ++q) {
        const unsigned yv = row[q];
        #pragma unroll
        for (int c = 0; c < 8; ++c)
          acc[c] = fdot2(yv, w1p[(i * NQ1 + q) * 8 + c], acc[c]);
      }
    }
    unsigned* hw = (unsigned*)h1_t + (f + 1) * (PC2 / 2);
    #pragma unroll
    for (int k = 0; k < 4; ++k)
      hw[k] = packh2(fmaxf(acc[2*k], 0.f), fmaxf(acc[2*k+1], 0.f));
  }
  if (tid < 8) {  // sidecar: f=256 (row 257), out-channel = tid
    float a = wb1[tid];
    const unsigned* yw = (const unsigned*)y_t;
    #pragma unroll
    for (int i = 0; i < 3; ++i) {
      const unsigned* row = yw + (256 + i) * (PC1 / 2);
      for (int q = 0; q < NQ1; ++q)
        a = fdot2(row[q], w1p[(i * NQ1 + q) * 8 + tid], a);
    }
    h1_t[257 * PC2 + tid] = f2h(fmaxf(a, 0.f));
  }
  __syncthreads();

  // ---- stage C: conv2 (f,8)->(f,8) via dot2, relu ----
  float ps1 = 0.f, ps2 = 0.f;
  {
    const int f = tid;
    float o2[8];
    #pragma unroll
    for (int c = 0; c < 8; ++c) o2[c] = wb2[c];
    const unsigned* hw = (const unsigned*)h1_t;
    #pragma unroll
    for (int i = 0; i < 3; ++i) {
      const unsigned* row = hw + (f + i) * (PC2 / 2);
      #pragma unroll
      for (int q = 0; q < 4; ++q) {
        const unsigned hv = row[q];
        #pragma unroll
        for (int c = 0; c < 8; ++c)
          o2[c] = fdot2(hv, w2p[(i*4 + q)*8 + c], o2[c]);
      }
    }
    if constexpr (!HEAD) {
      const size_t ob = (size_t)bt * FRS + (size_t)CIN * NF;
      #pragma unroll
      for (int c = 0; c < 8; ++c) {
        const __half hv = __float2half(fmaxf(o2[c], 0.f));
        Hout[ob + (size_t)c * NF + f] = hv;
        const float v = __half2float(hv);
        ps1 += v;
        ps2 = fmaf(v, v, ps2);
      }
    } else {
      unsigned* ow = (unsigned*)y_t + f * (PC1 / 2);  // out2_t row f (y_t dead)
      #pragma unroll
      for (int k = 0; k < 4; ++k)
        ow[k] = packh2(fmaxf(o2[2*k], 0.f), fmaxf(o2[2*k+1], 0.f));
    }
  }
  if (tid >= 8 && tid < 16) {  // sidecar: f=256, ch = tid-8
    const int c8 = tid - 8;
    float a = wb2[c8];
    const unsigned* hw = (const unsigned*)h1_t;
    #pragma unroll
    for (int i = 0; i < 3; ++i) {
      const unsigned* row = hw + (256 + i) * (PC2 / 2);
      #pragma unroll
      for (int q = 0; q < 4; ++q)
        a = fdot2(row[q], w2p[(i*4 + q)*8 + c8], a);
    }
    if constexpr (!HEAD) {
      const size_t ob = (size_t)bt * FRS + (size_t)CIN * NF;
      const __half hv = __float2half(fmaxf(a, 0.f));
      Hout[ob + (size_t)c8 * NF + 256] = hv;
      const float v = __half2float(hv);
      ps1 += v;
      ps2 = fmaf(v, v, ps2);
    } else {
      y_t[256 * PC1 + c8] = f2h(fmaxf(a, 0.f));
    }
  }

  if constexpr (!HEAD) {
    #pragma unroll
    for (int off = 32; off > 0; off >>= 1) {
      ps1 += __shfl_down(ps1, off, 64);
      ps2 += __shfl_down(ps2, off, 64);
    }
    if ((tid & 63) == 0) { red[(tid >> 6)*2] = ps1; red[(tid >> 6)*2+1] = ps2; }
    __syncthreads();
    if (tid == 0) {
      stats_out[bt*2]     = red[0] + red[2] + red[4] + red[6];
      stats_out[bt*2 + 1] = red[1] + red[3] + red[5] + red[7];
    }
  } else {
    __syncthreads();  // out2_t complete
    // ---- stage D: fc1 (valid k=3, 32ch) + relu + fc2 + sigmoid ----
    float part = 0.f;
    if (tid < NF - 2) {
      const unsigned short* xgu = (const unsigned short*)F2;  // frame t, L1-warm
      float acc = fc1b[0];
      #pragma unroll
      for (int i = 0; i < 3; ++i) {
        const int pos = tid + i;
        for (int q = 0; q < 12; ++q) {   // raw-input channel pairs
          const unsigned lo = xgu[(2*q) * 257 + pos];
          const unsigned hi = xgu[(2*q + 1) * 257 + pos];
          acc = fdot2(lo | (hi << 16), wfc1p[i*16 + q], acc);
        }
        const unsigned* orow = (const unsigned*)y_t + pos * (PC1 / 2);
        #pragma unroll
        for (int q = 0; q < 4; ++q)      // this layer's 8 output channels
          acc = fdot2(orow[q], wfc1p[i*16 + 12 + q], acc);
      }
      part = fmaxf(acc, 0.f) * fc2W[tid];
    }
    #pragma unroll
    for (int off = 32; off > 0; off >>= 1) part += __shfl_down(part, off, 64);
    if ((tid & 63) == 0) red[tid >> 6] = part;
    __syncthreads();
    if (tid == 0) {
      const float tot = red[0] + red[1] + red[2] + red[3] + fc2b[0];
      out[bt] = 1.0f / (1.0f + expf(-tot));
    }
  }
}

}  // namespace

extern "C" void kernel_launch(void* const* d_in, const int* in_sizes, int n_in,
                              void* d_out, int out_size, void* d_ws, size_t ws_size,
                              hipStream_t stream) {
  (void)in_sizes; (void)n_in; (void)out_size; (void)ws_size;
  const float* x = (const float*)d_in[0];
  float* out = (float*)d_out;
  char*  wsb = (char*)d_ws;

  __half* H   = (__half*)wsb;                       // NBT*FRS halfs = ~101 MB
  char* p = wsb + (size_t)NBT * FRS * sizeof(__half);
  float* st0  = (float*)p; p += 2 * NBT * sizeof(float);
  float* st1  = (float*)p; p += 2 * NBT * sizeof(float);
  float* st2  = (float*)p; p += 2 * NBT * sizeof(float);
  __half* tbl1 = (__half*)p; p += 6 * (8  * NF) * sizeof(__half);
  __half* tbl2 = (__half*)p; p += 6 * (16 * NF) * sizeof(__half);
  __half* tbl3 = (__half*)p;

  dim3 blk(256);

  fold_all<<<dim3((48 * 257 + 255) / 256), blk, 0, stream>>>(
      (const float*)d_in[5],  (const float*)d_in[6],  (const float*)d_in[7],  tbl1,
      (const float*)d_in[12], (const float*)d_in[13], (const float*)d_in[14], tbl2,
      (const float*)d_in[19], (const float*)d_in[20], (const float*)d_in[21], tbl3);

  stft_l0_kernel<<<dim3(NBT), blk, 0, stream>>>(
      x, (const float*)d_in[1], (const float*)d_in[2],
      (const float*)d_in[3], (const float*)d_in[4], H, st0);

  layer_bt<8, false><<<dim3(NBT), blk, 0, stream>>>(
      H, H, st0, nullptr, nullptr, st1, tbl1,
      (const float*)d_in[8], (const float*)d_in[9],
      (const float*)d_in[10], (const float*)d_in[11],
      nullptr, nullptr, nullptr, nullptr, nullptr);

  layer_bt<16, false><<<dim3(NBT), blk, 0, stream>>>(
      H, H, st0, st1, nullptr, st2, tbl2,
      (const float*)d_in[15], (const float*)d_in[16],
      (const float*)d_in[17], (const float*)d_in[18],
      nullptr, nullptr, nullptr, nullptr, nullptr);

  layer_bt<24, true><<<dim3(NBT), blk, 0, stream>>>(
      H, nullptr, st0, st1, st2, nullptr, tbl3,
      (const float*)d_in[22], (const float*)d_in[23],
      (const float*)d_in[24], (const float*)d_in[25],
      (const float*)d_in[26], (const float*)d_in[27],
      (const float*)d_in[28], (const float*)d_in[29],
      out);
}